// Round 10
// baseline (66.491 us; speedup 1.0000x reference)
//
#include <hip/hip_runtime.h>

#define TOKENS 16384
#define KDIM   2048
#define NEXP   64
#define TOPK   6
#define NSTEPS (KDIM / 32)        // 64 global K-steps

typedef short short8 __attribute__((ext_vector_type(8)));   // 8 bf16 = 4 VGPR
typedef float f32x4  __attribute__((ext_vector_type(4)));

// Exact 3-way truncation split: f == bf(h) + bf(l) + bf(l2) + eps, |eps| <= 2^-24 |f|.
__device__ __forceinline__ void split3(float f, short& h, short& l, short& l2) {
  const unsigned u = __builtin_bit_cast(unsigned, f);
  h = (short)(u >> 16);
  const float r1 = f - __builtin_bit_cast(float, u & 0xffff0000u);
  const unsigned u1 = __builtin_bit_cast(unsigned, r1);
  l = (short)(u1 >> 16);
  const float r2 = r1 - __builtin_bit_cast(float, u1 & 0xffff0000u);
  l2 = (short)(__builtin_bit_cast(unsigned, r2) >> 16);
}

// Kernel 0: pack W into MFMA-B-fragment order, 3-term bf16 split.
// w*[s][nt][lane][j] = term of W[s*32 + (lane>>4)*8 + j][nt*16 + (lane&15)]
__global__ __launch_bounds__(256)
void moe_wpack(const float* __restrict__ wg, short* __restrict__ wh,
               short* __restrict__ wl, short* __restrict__ wl2) {
  const int tid = blockIdx.x * 256 + threadIdx.x;  // 0..16383 = (s, nt, lane)
  const int l  = tid & 63;
  const int nt = (tid >> 6) & 3;
  const int s  = tid >> 8;
  short8 a, b, c;
#pragma unroll
  for (int j = 0; j < 8; ++j) {
    const int k = s * 32 + (l >> 4) * 8 + j;
    const int n = nt * 16 + (l & 15);
    short xh, xl, xl2;
    split3(wg[(size_t)k * NEXP + n], xh, xl, xl2);
    a[j] = xh; b[j] = xl; c[j] = xl2;
  }
  *(short8*)(wh  + (size_t)tid * 8) = a;
  *(short8*)(wl  + (size_t)tid * 8) = b;
  *(short8*)(wl2 + (size_t)tid * 8) = c;
}

// Kernel 1: fully fused GEMM + softmax + top-k. Grid 1024 x 256 -> 4 blocks/CU
// = 16 waves/CU (the TLP), NO main-loop barriers, NO LDS staging, NO part[].
// Block b: tokens b*16..+15. Wave wid: expert-half eh=wid&1 (2 tiles),
// K-half kh=wid>>1 (32 steps of 32 k). x A-fragments load straight to VGPR
// (lane = row l&15, k-group l>>4; waves sharing a k-half hit L1); w fragments
// stream from the packed L2-resident arrays. 6-term bf16-split MFMA as proven
// in r4-r9. Epilogue: 2-way k-reduction via LDS, then in-block softmax+top-k.
__global__ __launch_bounds__(256, 4)
void moe_fused(const float* __restrict__ x, const short* __restrict__ wh,
               const short* __restrict__ wl, const short* __restrict__ wl2,
               float* __restrict__ out) {
  __shared__ float red[2][64][8];   // k-high partials: [eh][lane][tt*4+r], 4 KB
  __shared__ float lg[16][NEXP];    // reduced logits, 4 KB

  const int t    = threadIdx.x;
  const int lane = t & 63;
  const int wid  = t >> 6;
  const int row0 = blockIdx.x * 16;
  const int eh   = wid & 1;        // expert half: tiles nt = eh*2, eh*2+1
  const int kh   = wid >> 1;       // K half
  const int r15  = lane & 15;      // token row within tile
  const int kb   = lane >> 4;      // k-subgroup (8 k each)

  f32x4 accB[2] = {};   // hh term per tile
  f32x4 accS[2] = {};   // correction terms per tile

  const short8* __restrict__ whv  = (const short8*)wh;
  const short8* __restrict__ wlv  = (const short8*)wl;
  const short8* __restrict__ wl2v = (const short8*)wl2;

  const float* xrow = x + (size_t)(row0 + r15) * KDIM + kh * (KDIM / 2) + kb * 8;

#pragma unroll 2
  for (int c = 0; c < 32; ++c) {
    // A fragment: 8 floats straight from global (L1-shared with partner wave)
    const float4 xa = *(const float4*)(xrow + c * 32);
    const float4 xb = *(const float4*)(xrow + c * 32 + 4);
    short8 ah, al, al2;
#pragma unroll
    for (int e = 0; e < 4; ++e) {
      short h0, l0, m0, h1, l1, m1;
      split3(((const float*)&xa)[e], h0, l0, m0);
      split3(((const float*)&xb)[e], h1, l1, m1);
      ah[e] = h0; al[e] = l0; al2[e] = m0;
      ah[e + 4] = h1; al[e + 4] = l1; al2[e + 4] = m1;
    }
    const int s = kh * 32 + c;
#pragma unroll
    for (int tt = 0; tt < 2; ++tt) {
      const int fi = (s * 4 + eh * 2 + tt) * 64 + lane;
      const short8 bh  = whv[fi];
      const short8 bl  = wlv[fi];
      const short8 bl2 = wl2v[fi];
      accB[tt] = __builtin_amdgcn_mfma_f32_16x16x32_bf16(ah,  bh,  accB[tt], 0, 0, 0);
      accS[tt] = __builtin_amdgcn_mfma_f32_16x16x32_bf16(al,  bh,  accS[tt], 0, 0, 0);
      accS[tt] = __builtin_amdgcn_mfma_f32_16x16x32_bf16(ah,  bl,  accS[tt], 0, 0, 0);
      accS[tt] = __builtin_amdgcn_mfma_f32_16x16x32_bf16(al,  bl,  accS[tt], 0, 0, 0);
      accS[tt] = __builtin_amdgcn_mfma_f32_16x16x32_bf16(ah,  bl2, accS[tt], 0, 0, 0);
      accS[tt] = __builtin_amdgcn_mfma_f32_16x16x32_bf16(al2, bh,  accS[tt], 0, 0, 0);
    }
  }

  // ---- 2-way k-reduction. D: col=lane&15 (expert in tile), row=(lane>>4)*4+r.
  if (kh == 1) {
#pragma unroll
    for (int tt = 0; tt < 2; ++tt)
#pragma unroll
      for (int r = 0; r < 4; ++r)
        red[eh][lane][tt * 4 + r] = accB[tt][r] + accS[tt][r];
  }
  __syncthreads();
  if (kh == 0) {
#pragma unroll
    for (int tt = 0; tt < 2; ++tt)
#pragma unroll
      for (int r = 0; r < 4; ++r)
        lg[(lane >> 4) * 4 + r][(eh * 2 + tt) * 16 + r15] =
            accB[tt][r] + accS[tt][r] + red[eh][lane][tt * 4 + r];
  }
  __syncthreads();

  // ---- softmax + top-k: 16 lanes per token, 4 experts/lane (proven r0 code)
  const int sub  = lane & 15;
  const int tokL = wid * 4 + (lane >> 4);
  float v[4];
  {
    const float4 p = *(const float4*)(&lg[tokL][sub * 4]);
    v[0] = p.x; v[1] = p.y; v[2] = p.z; v[3] = p.w;
  }

  float m = fmaxf(fmaxf(v[0], v[1]), fmaxf(v[2], v[3]));
#pragma unroll
  for (int off = 1; off < 16; off <<= 1) m = fmaxf(m, __shfl_xor(m, off));
  const float p0 = expf(v[0] - m), p1 = expf(v[1] - m);
  const float p2 = expf(v[2] - m), p3 = expf(v[3] - m);
  float s = p0 + p1 + p2 + p3;
#pragma unroll
  for (int off = 1; off < 16; off <<= 1) s += __shfl_xor(s, off);
  v[0] = p0 / s; v[1] = p1 / s; v[2] = p2 / s; v[3] = p3 / s;

  float resv = 0.f; int resi = 0;
#pragma unroll
  for (int rr = 0; rr < TOPK; ++rr) {
    float bv = v[0]; int bi = sub * 4;
#pragma unroll
    for (int j = 1; j < 4; ++j)
      if (v[j] > bv) { bv = v[j]; bi = sub * 4 + j; }   // strict > : lowest idx on tie
#pragma unroll
    for (int off = 1; off < 16; off <<= 1) {
      const float ov = __shfl_xor(bv, off);
      const int   oi = __shfl_xor(bi, off);
      if (ov > bv || (ov == bv && oi < bi)) { bv = ov; bi = oi; }
    }
    if (sub == rr) { resv = bv; resi = bi; }
    if ((bi >> 2) == sub) v[bi & 3] = -1.f;   // scores > 0, sentinel safe
  }

  if (sub < TOPK) {
    const int tok = row0 + tokL;
    out[(size_t)tok * TOPK + sub] = (float)resi;
    out[(size_t)TOKENS * TOPK + (size_t)tok * TOPK + sub] = resv;
  }
}

extern "C" void kernel_launch(void* const* d_in, const int* in_sizes, int n_in,
                              void* d_out, int out_size, void* d_ws, size_t ws_size,
                              hipStream_t stream) {
  const float* x  = (const float*)d_in[0];
  const float* wg = (const float*)d_in[1];
  float* out = (float*)d_out;

  short* wh  = (short*)d_ws;                        // 3 x 131072 shorts = 768 KB
  short* wl  = wh + (size_t)NSTEPS * 4 * 64 * 8;
  short* wl2 = wl + (size_t)NSTEPS * 4 * 64 * 8;

  moe_wpack<<<dim3(64), dim3(256), 0, stream>>>(wg, wh, wl, wl2);
  moe_fused<<<dim3(TOKENS / 16), dim3(256), 0, stream>>>(x, wh, wl, wl2, out);
}